// Round 11
// baseline (487.291 us; speedup 1.0000x reference)
//
#include <hip/hip_runtime.h>
#include <hip/hip_bf16.h>
#include <math.h>

// Problem dims
#define BB 8
#define TT 16
#define HH 112
#define WW 112
#define CC 3
#define FF 16
#define HP 56
#define WP 56
#define HO 54
#define WO 54
#define NC 6

#define NPIX (BB*HO*WO)               // 23328
#define SPIX (HO*WO)                  // 2916
#define NPT  (BB*TT*SPIX)             // 373248  (b,t,pixel)

// ws layout (float offsets)
#define POOLED_ELEMS (128*56*56*16)   // 6,422,528
#define HSTATE_ELEMS (BB*SPIX*16)     // 373,248
// wrpack [8 cg][9 tap][16 ci][2 c][4 g] = 9216 floats (zx uses wk directly)
#define WPACK_ELEMS  9216

typedef __attribute__((ext_vector_type(2))) float f2;

__device__ __forceinline__ float hsig(float x) {
    return fminf(fmaxf(0.2f*x + 0.5f, 0.0f), 1.0f);
}
__device__ __forceinline__ f2 f2max(f2 a, f2 b) {
    f2 r; r.x = fmaxf(a.x, b.x); r.y = fmaxf(a.y, b.y); return r;
}

// Kernel 0: repack wr into [cg8][tap][ci][c2][g] (step-kernel consumer layout).
__global__ __launch_bounds__(256) void repack_kernel(
    const float* __restrict__ wr, float* __restrict__ wpack)
{
    int j = blockIdx.x * 256 + threadIdx.x;        // 36*256 = 9216 exact
    int g   = j & 3;
    int c   = (j >> 2) & 1;
    int ci  = (j >> 3) & 15;
    int tap = (j >> 7) % 9;
    int cg8 = (j >> 7) / 9;
    wpack[j] = wr[tap*1024 + ci*64 + g*16 + cg8*2 + c];
}

// Kernel 1: fused 7x7 SAME conv (3->16) + bias + relu + 2x2 maxpool.
// Block = 28x8 pooled tile, input tile 62x22x3 staged in LDS (16.4 KB).
// 588 scattered global loads/thread -> short-latency ds_reads overlapped
// with FMA issue. kx loop unroll 1 keeps 48 scalar weights live (no SGPR
// blowup, no dynamic register indexing).
__global__ __launch_bounds__(256, 4) void conv_pool_kernel(
    const float* __restrict__ x,      // [128,112,112,3]
    const float* __restrict__ cw,     // [7,7,3,16]
    const float* __restrict__ cb,     // [16]
    float* __restrict__ pooled)       // [128,56,56,16]
{
    int fr = blockIdx.y;
    int tx = blockIdx.x & 1, ty = blockIdx.x >> 1;   // 2 x 7 tiles
    int col0 = tx*28, row0 = ty*8;
    int tid = threadIdx.x;
    const float* xf = x + (size_t)fr * (HH*WW*CC);

    __shared__ float xs[22*62*3];     // rows 2*row0-3 .. +21, cols 2*col0-3 .. +61
    {
        int ir0 = 2*row0 - 3;
        int ic3 = (2*col0 - 3) * 3;
        #pragma unroll 1
        for (int i = tid; i < 22*62*3; i += 256) {
            int iy = i / 186, rem = i - iy*186;
            int gr = ir0 + iy;
            int gc3 = ic3 + rem;
            bool ok = (gr >= 0) & (gr < HH) & (gc3 >= 0) & (gc3 < WW*3);
            xs[i] = ok ? xf[gr*(WW*3) + gc3] : 0.f;
        }
    }
    __syncthreads();

    if (tid >= 224) return;
    int lx = tid % 28, ly = tid / 28;   // ly 0..7

    const f2* cb2 = (const f2*)cb;
    f2 best[8];
    #pragma unroll
    for (int i = 0; i < 8; ++i) { best[i].x = -1e30f; best[i].y = -1e30f; }

    #pragma unroll 1
    for (int pos = 0; pos < 4; ++pos) {
        int py = pos >> 1, px = pos & 1;
        f2 acc[8];
        #pragma unroll
        for (int i = 0; i < 8; ++i) acc[i] = cb2[i];
        #pragma unroll 1
        for (int ky = 0; ky < 7; ++ky) {
            const float* rowp = &xs[((2*ly + py + ky)*62 + (2*lx + px))*3];
            #pragma unroll 1
            for (int kx = 0; kx < 7; ++kx) {
                const f2* wv = (const f2*)(cw + ((ky*7 + kx)*3)*16);
                #pragma unroll
                for (int ci = 0; ci < 3; ++ci) {
                    float a = rowp[kx*3 + ci];
                    #pragma unroll
                    for (int i8 = 0; i8 < 8; ++i8)
                        acc[i8] += a * wv[ci*8 + i8];
                }
            }
        }
        #pragma unroll
        for (int i = 0; i < 8; ++i) best[i] = f2max(best[i], acc[i]);
    }

    int pr = row0 + ly, pc = col0 + lx;
    float4* op = (float4*)(pooled + (((size_t)fr*HP + pr)*WP + pc)*16);
    #pragma unroll
    for (int v = 0; v < 4; ++v) {
        float4 o;
        o.x = fmaxf(best[v*2+0].x, 0.0f);
        o.y = fmaxf(best[v*2+0].y, 0.0f);
        o.z = fmaxf(best[v*2+1].x, 0.0f);
        o.w = fmaxf(best[v*2+1].y, 0.0f);
        op[v] = o;
    }
}

// Kernel 2a: precompute zx = conv3x3 VALID (pooled -> 64 gates) for ALL t.
// Thread = one (b,t,pixel) x ALL 64 gates (acc f2[32] ~ 90 VGPR): kills the
// 4x redundant pooled loads of the cg-split version. Weights = wk as-is
// ([tap][ci][64] is already gate-plane order), 64-float scalar chunks per ci
// (ci loop unroll 1 -- the proven anti-spill pattern).
__global__ __launch_bounds__(256, 4) void zx_all_kernel(
    const float* __restrict__ pooled,   // [128,56,56,16]
    const float* __restrict__ wk,       // [3,3,16,64] original
    __hip_bfloat16* __restrict__ zx)    // [64][373248]
{
    int pt = blockIdx.x * 256 + threadIdx.x;   // 1458*256 = 373248 exact
    int b  = pt / (TT*SPIX);
    int rt = pt % (TT*SPIX);
    int tt = rt / SPIX;
    int r  = rt % SPIX;
    int oh = r / WO, ow = r % WO;

    const float* pf = pooled + (size_t)(b*TT + tt) * HP * WP * 16;

    f2 acc[32];                         // plane pairs (2g, 2g+1)
    #pragma unroll
    for (int i = 0; i < 32; ++i) { acc[i].x = 0.f; acc[i].y = 0.f; }

    #pragma unroll 1
    for (int tap = 0; tap < 9; ++tap) {
        int ky = tap / 3;
        int kx = tap - ky * 3;
        const float4* pp = (const float4*)(pf + ((size_t)(oh+ky) * WP + (ow+kx)) * 16);
        float a[16];
        #pragma unroll
        for (int v = 0; v < 4; ++v) {
            float4 x4 = pp[v];
            a[v*4+0] = x4.x; a[v*4+1] = x4.y; a[v*4+2] = x4.z; a[v*4+3] = x4.w;
        }
        const float* wt = wk + tap * 1024;
        #pragma unroll 1
        for (int ci = 0; ci < 16; ++ci) {       // 64 scalar floats live/iter
            float av = a[ci];
            const f2* wv = (const f2*)(wt + ci * 64);
            #pragma unroll
            for (int g = 0; g < 32; ++g)
                acc[g] += av * wv[g];
        }
    }

    #pragma unroll
    for (int g = 0; g < 32; ++g) {
        zx[(size_t)(2*g + 0) * NPT + pt] = __float2bfloat16(acc[g].x);
        zx[(size_t)(2*g + 1) * NPT + pt] = __float2bfloat16(acc[g].y);
    }
}

// Kernel 2b: one ConvLSTM step (unchanged from R9: planar LDS h-tile,
// conflict-free b128, 8-way cg split, scalar wr weights).
__global__ __launch_bounds__(256, 4) void lstm_step_kernel(
    const __hip_bfloat16* __restrict__ zx,  // [64][373248]
    const float* __restrict__ h_in,         // [8,54,54,16]
    float* __restrict__ h_out,
    float* __restrict__ cst,
    const float* __restrict__ wrpack,       // [cg8][tap][ci][c2][g]
    const float* __restrict__ bias,         // [64]
    int t)
{
    int tileid = blockIdx.x;      // 0..11
    int tx = tileid % 3;
    int ty = tileid / 3;
    int b  = blockIdx.y;
    int cg = blockIdx.z;          // 0..7, channels cg*2, cg*2+1
    const float* wcg = wrpack + cg * 1152;

    int tid = threadIdx.x;
    int lx = tid % 18, ly = tid / 18;
    int gx = tx*18 + lx;
    int gy = ty*14 + ly;
    bool active = (tid < 252) && (gy < HO);

    const float* hb = h_in + (size_t)b * SPIX * 16;

    __shared__ float4 htileV[4][320];   // planar: 16B lane stride, conflict-free
    {
        int gy0 = ty*14 - 1, gx0 = tx*18 - 1;
        for (int i = tid; i < 320; i += 256) {
            int iy = i / 20, ix = i % 20;
            int hy = gy0 + iy, hx = gx0 + ix;
            bool ok = (hy >= 0) & (hy < HO) & (hx >= 0) & (hx < WO);
            const float4* src = (const float4*)(hb + ((size_t)hy * WO + hx) * 16);
            #pragma unroll
            for (int v = 0; v < 4; ++v)
                htileV[v][i] = ok ? src[v] : make_float4(0.f, 0.f, 0.f, 0.f);
        }
    }
    __syncthreads();

    if (!active) return;

    int r = gy * WO + gx;
    size_t pt = (size_t)b * (TT*SPIX) + (size_t)t * SPIX + r;
    int ch0 = cg * 2;

    float z[8];
    #pragma unroll
    for (int c = 0; c < 2; ++c)
        #pragma unroll
        for (int g = 0; g < 4; ++g)
            z[c*4 + g] = __bfloat162float(zx[(size_t)(g*16 + ch0 + c) * NPT + pt]);

    f2 acc[4];
    #pragma unroll
    for (int i = 0; i < 4; ++i) { acc[i].x = 0.f; acc[i].y = 0.f; }

    #pragma unroll 1
    for (int tap = 0; tap < 9; ++tap) {
        int ky = tap / 3;
        int kx = tap - ky * 3;
        int pix = (ly + ky)*20 + (lx + kx);
        float h[16];
        #pragma unroll
        for (int v = 0; v < 4; ++v) {
            float4 t4 = htileV[v][pix];
            h[v*4+0] = t4.x; h[v*4+1] = t4.y; h[v*4+2] = t4.z; h[v*4+3] = t4.w;
        }
        const float* wt = wcg + tap * 128;
        #pragma unroll 1
        for (int hf = 0; hf < 2; ++hf) {
            const f2* wv = (const f2*)(wt + hf * 64);
            #pragma unroll
            for (int u = 0; u < 8; ++u) {
                float hv = h[hf*8 + u];
                acc[0] += hv * wv[u*4 + 0];
                acc[1] += hv * wv[u*4 + 1];
                acc[2] += hv * wv[u*4 + 2];
                acc[3] += hv * wv[u*4 + 3];
            }
        }
    }

    size_t base = ((size_t)(b * SPIX + r)) * 16 + ch0;
    float2 cold = *(float2*)&cst[base];
    float cn[2], hn[2];
    #pragma unroll
    for (int c = 0; c < 2; ++c) {
        float iv = hsig(z[c*4+0] + acc[c*2+0].x + bias[ 0 + ch0 + c]);
        float fv = hsig(z[c*4+1] + acc[c*2+0].y + bias[16 + ch0 + c]);
        float gv = tanhf(z[c*4+2] + acc[c*2+1].x + bias[32 + ch0 + c]);
        float ov = hsig(z[c*4+3] + acc[c*2+1].y + bias[48 + ch0 + c]);
        float cold_c = (c == 0) ? cold.x : cold.y;
        cn[c] = fv * cold_c + iv * gv;
        hn[c] = ov * tanhf(cn[c]);
    }
    *(float2*)&cst[base]   = make_float2(cn[0], cn[1]);
    *(float2*)&h_out[base] = make_float2(hn[0], hn[1]);
}

// Kernel 3: spatial mean over 54x54 -> dense(16->6) -> softmax. One block per b.
__global__ __launch_bounds__(256) void head_kernel(
    const float* __restrict__ h,    // [8,54,54,16]
    const float* __restrict__ dw,   // [16,6]
    const float* __restrict__ db,   // [6]
    float* __restrict__ out)        // [8,6]
{
    int b = blockIdx.x;
    int tid = threadIdx.x;
    const float* hb = h + (size_t)b * SPIX * 16;
    float s = 0.0f;
    for (int i = tid; i < SPIX*16; i += 256) s += hb[i];
    __shared__ float red[256];
    red[tid] = s;
    __syncthreads();
    for (int st = 128; st >= 16; st >>= 1) {
        if (tid < st) red[tid] += red[tid + st];
        __syncthreads();
    }
    __shared__ float logits[8];
    if (tid < NC) {
        float l = db[tid];
        #pragma unroll
        for (int ch = 0; ch < 16; ++ch)
            l += (red[ch] * (1.0f/2916.0f)) * dw[ch*NC + tid];
        logits[tid] = l;
    }
    __syncthreads();
    if (tid < NC) {
        float m = -1e30f;
        for (int k = 0; k < NC; ++k) m = fmaxf(m, logits[k]);
        float e = expf(logits[tid] - m);
        float d = 0.0f;
        for (int k = 0; k < NC; ++k) d += expf(logits[k] - m);
        out[b*NC + tid] = e / d;
    }
}

extern "C" void kernel_launch(void* const* d_in, const int* in_sizes, int n_in,
                              void* d_out, int out_size, void* d_ws, size_t ws_size,
                              hipStream_t stream) {
    const float* x      = (const float*)d_in[0];
    const float* conv_w = (const float*)d_in[1];
    const float* conv_b = (const float*)d_in[2];
    const float* wk     = (const float*)d_in[3];
    const float* wr     = (const float*)d_in[4];
    const float* bias   = (const float*)d_in[5];
    const float* dw     = (const float*)d_in[6];
    const float* db     = (const float*)d_in[7];
    float* out = (float*)d_out;

    float* ws     = (float*)d_ws;
    float* pooled = ws;                                   // 6,422,528 f
    float* hA     = pooled + POOLED_ELEMS;                //   373,248 f
    float* hB     = hA + HSTATE_ELEMS;
    float* cbuf   = hB + HSTATE_ELEMS;
    float* wpack  = cbuf + HSTATE_ELEMS;                  //     9,216 f (wrpack)
    __hip_bfloat16* zx = (__hip_bfloat16*)(wpack + WPACK_ELEMS); // 47.8 MB

    // h0 = 0, c0 = 0 (ws is poisoned before every launch)
    hipMemsetAsync(hA,   0, HSTATE_ELEMS * sizeof(float), stream);
    hipMemsetAsync(cbuf, 0, HSTATE_ELEMS * sizeof(float), stream);

    repack_kernel<<<dim3(36), dim3(256), 0, stream>>>(wr, wpack);
    conv_pool_kernel<<<dim3(14, 128), dim3(256), 0, stream>>>(x, conv_w, conv_b, pooled);
    zx_all_kernel<<<dim3(1458), dim3(256), 0, stream>>>(pooled, wk, zx);

    for (int t = 0; t < TT; ++t) {
        const float* hin  = (t & 1) ? hB : hA;
        float*       hout = (t & 1) ? hA : hB;
        lstm_step_kernel<<<dim3(12, 8, 8), dim3(256), 0, stream>>>(
            zx, hin, hout, cbuf, wpack, bias, t);
    }
    // t=15 (odd) wrote hA
    head_kernel<<<dim3(8), dim3(256), 0, stream>>>(hA, dw, db, out);
}

// Round 12
// 483.378 us; speedup vs baseline: 1.0081x; 1.0081x over previous
//
#include <hip/hip_runtime.h>
#include <hip/hip_bf16.h>
#include <math.h>

// Problem dims
#define BB 8
#define TT 16
#define HH 112
#define WW 112
#define CC 3
#define FF 16
#define HP 56
#define WP 56
#define HO 54
#define WO 54
#define NC 6

#define NPIX (BB*HO*WO)               // 23328
#define SPIX (HO*WO)                  // 2916
#define NPT  (BB*TT*SPIX)             // 373248  (b,t,pixel)

// ws layout (float offsets)
#define POOLED_ELEMS (128*56*56*16)   // 6,422,528
#define HSTATE_ELEMS (BB*SPIX*16)     // 373,248
#define WPACK_ELEMS  9216             // wrpack [8 cg][9 tap][16 ci][2 c][4 g]

typedef __attribute__((ext_vector_type(2))) float f2;

__device__ __forceinline__ float hsig(float x) {
    return fminf(fmaxf(0.2f*x + 0.5f, 0.0f), 1.0f);
}
__device__ __forceinline__ f2 f2max(f2 a, f2 b) {
    f2 r; r.x = fmaxf(a.x, b.x); r.y = fmaxf(a.y, b.y); return r;
}

// Kernel 0: repack wr into [cg8][tap][ci][c2][g] (step-kernel consumer layout).
__global__ __launch_bounds__(256) void repack_kernel(
    const float* __restrict__ wr, float* __restrict__ wpack)
{
    int j = blockIdx.x * 256 + threadIdx.x;        // 36*256 = 9216 exact
    int g   = j & 3;
    int c   = (j >> 2) & 1;
    int ci  = (j >> 3) & 15;
    int tap = (j >> 7) % 9;
    int cg8 = (j >> 7) / 9;
    wpack[j] = wr[tap*1024 + ci*64 + g*16 + cg8*2 + c];
}

// Kernel 1: fused 7x7 SAME conv (3->16) + bias + relu + 2x2 maxpool.
// LDS input tile in PARITY PLANES: xs[p][row][m][ci] where global column
// c = 2m+p. Compute reads column 2lx+px+kx -> plane (px+kx)&1, m=lx+((px+kx)>>1)
// -> lane stride 3 floats, gcd(3,32)=1 -> 2 lanes/bank = conflict-free.
// (R10 interleaved layout had lane stride 6 -> 4-way, 1.37e7 conflicts.)
__global__ __launch_bounds__(256, 4) void conv_pool_kernel(
    const float* __restrict__ x,      // [128,112,112,3]
    const float* __restrict__ cw,     // [7,7,3,16]
    const float* __restrict__ cb,     // [16]
    float* __restrict__ pooled)       // [128,56,56,16]
{
    int fr = blockIdx.y;
    int tx = blockIdx.x & 1, ty = blockIdx.x >> 1;   // 2 x 7 tiles
    int col0 = tx*28, row0 = ty*8;
    int tid = threadIdx.x;
    const float* xf = x + (size_t)fr * (HH*WW*CC);

    // planes: p in {0,1}, 22 rows, 31 half-columns, 3 ch  -> 4092 floats
    __shared__ float xs[2*22*31*3];
    {
        int ir0 = 2*row0 - 3;
        int ic0 = 2*col0 - 3;
        #pragma unroll 1
        for (int i = tid; i < 22*62*3; i += 256) {
            int iy  = i / 186;
            int rem = i - iy*186;
            int c   = rem / 3;
            int ci  = rem - c*3;
            int gr = ir0 + iy;
            int gc = ic0 + c;
            bool ok = (gr >= 0) & (gr < HH) & (gc >= 0) & (gc < WW);
            float v = ok ? xf[(gr*WW + gc)*3 + ci] : 0.f;
            xs[(c & 1)*2046 + iy*93 + (c >> 1)*3 + ci] = v;
        }
    }
    __syncthreads();

    if (tid >= 224) return;
    int lx = tid % 28, ly = tid / 28;   // ly 0..7

    const f2* cb2 = (const f2*)cb;
    f2 best[8];
    #pragma unroll
    for (int i = 0; i < 8; ++i) { best[i].x = -1e30f; best[i].y = -1e30f; }

    #pragma unroll 1
    for (int pos = 0; pos < 4; ++pos) {
        int py = pos >> 1, px = pos & 1;
        f2 acc[8];
        #pragma unroll
        for (int i = 0; i < 8; ++i) acc[i] = cb2[i];
        #pragma unroll 1
        for (int ky = 0; ky < 7; ++ky) {
            int row = 2*ly + py + ky;           // 0..21
            const float* rowbase = &xs[row*93 + lx*3];
            #pragma unroll 1
            for (int kx = 0; kx < 7; ++kx) {
                int s = px + kx;                // 0..7
                const float* xp = rowbase + (s & 1)*2046 + (s >> 1)*3;
                const f2* wv = (const f2*)(cw + ((ky*7 + kx)*3)*16);
                #pragma unroll
                for (int ci = 0; ci < 3; ++ci) {
                    float a = xp[ci];
                    #pragma unroll
                    for (int i8 = 0; i8 < 8; ++i8)
                        acc[i8] += a * wv[ci*8 + i8];
                }
            }
        }
        #pragma unroll
        for (int i = 0; i < 8; ++i) best[i] = f2max(best[i], acc[i]);
    }

    int pr = row0 + ly, pc = col0 + lx;
    float4* op = (float4*)(pooled + (((size_t)fr*HP + pr)*WP + pc)*16);
    #pragma unroll
    for (int v = 0; v < 4; ++v) {
        float4 o;
        o.x = fmaxf(best[v*2+0].x, 0.0f);
        o.y = fmaxf(best[v*2+0].y, 0.0f);
        o.z = fmaxf(best[v*2+1].x, 0.0f);
        o.w = fmaxf(best[v*2+1].y, 0.0f);
        op[v] = o;
    }
}

// Kernel 2a: precompute zx = conv3x3 VALID (pooled -> 64 gates) for ALL t.
// 2-way gate split (blockIdx.y = gate half): acc f2[16] = 32 floats keeps
// VGPR ~64 -> 8 waves/SIMD residency (R10's 64-gate merge hit a VGPR
// occupancy cliff: 34% occ, VALUBusy 45%). 11664 waves hide s_load/global
// latency; activation loads 2x but L1/L2-hot.
__global__ __launch_bounds__(256, 4) void zx_all_kernel(
    const float* __restrict__ pooled,   // [128,56,56,16]
    const float* __restrict__ wk,       // [3,3,16,64] original
    __hip_bfloat16* __restrict__ zx)    // [64][373248]
{
    int gh = blockIdx.y;                // 0..1, gate planes gh*32 .. gh*32+31
    int pt = blockIdx.x * 256 + threadIdx.x;   // 1458*256 = 373248 exact
    int b  = pt / (TT*SPIX);
    int rt = pt % (TT*SPIX);
    int tt = rt / SPIX;
    int r  = rt % SPIX;
    int oh = r / WO, ow = r % WO;

    const float* pf = pooled + (size_t)(b*TT + tt) * HP * WP * 16;

    f2 acc[16];                         // plane pairs within this half
    #pragma unroll
    for (int i = 0; i < 16; ++i) { acc[i].x = 0.f; acc[i].y = 0.f; }

    #pragma unroll 1
    for (int tap = 0; tap < 9; ++tap) {
        int ky = tap / 3;
        int kx = tap - ky * 3;
        const float4* pp = (const float4*)(pf + ((size_t)(oh+ky) * WP + (ow+kx)) * 16);
        float a[16];
        #pragma unroll
        for (int v = 0; v < 4; ++v) {
            float4 x4 = pp[v];
            a[v*4+0] = x4.x; a[v*4+1] = x4.y; a[v*4+2] = x4.z; a[v*4+3] = x4.w;
        }
        const float* wt = wk + tap * 1024 + gh * 32;
        #pragma unroll 1
        for (int ci = 0; ci < 16; ++ci) {       // 32 scalar floats live/iter
            float av = a[ci];
            const f2* wv = (const f2*)(wt + ci * 64);
            #pragma unroll
            for (int g = 0; g < 16; ++g)
                acc[g] += av * wv[g];
        }
    }

    #pragma unroll
    for (int g = 0; g < 16; ++g) {
        zx[(size_t)(gh*32 + 2*g + 0) * NPT + pt] = __float2bfloat16(acc[g].x);
        zx[(size_t)(gh*32 + 2*g + 1) * NPT + pt] = __float2bfloat16(acc[g].y);
    }
}

// Kernel 2b: one ConvLSTM step (unchanged from R9: planar LDS h-tile,
// conflict-free b128, 8-way cg split, scalar wr weights).
__global__ __launch_bounds__(256, 4) void lstm_step_kernel(
    const __hip_bfloat16* __restrict__ zx,  // [64][373248]
    const float* __restrict__ h_in,         // [8,54,54,16]
    float* __restrict__ h_out,
    float* __restrict__ cst,
    const float* __restrict__ wrpack,       // [cg8][tap][ci][c2][g]
    const float* __restrict__ bias,         // [64]
    int t)
{
    int tileid = blockIdx.x;      // 0..11
    int tx = tileid % 3;
    int ty = tileid / 3;
    int b  = blockIdx.y;
    int cg = blockIdx.z;          // 0..7, channels cg*2, cg*2+1
    const float* wcg = wrpack + cg * 1152;

    int tid = threadIdx.x;
    int lx = tid % 18, ly = tid / 18;
    int gx = tx*18 + lx;
    int gy = ty*14 + ly;
    bool active = (tid < 252) && (gy < HO);

    const float* hb = h_in + (size_t)b * SPIX * 16;

    __shared__ float4 htileV[4][320];   // planar: 16B lane stride, conflict-free
    {
        int gy0 = ty*14 - 1, gx0 = tx*18 - 1;
        for (int i = tid; i < 320; i += 256) {
            int iy = i / 20, ix = i % 20;
            int hy = gy0 + iy, hx = gx0 + ix;
            bool ok = (hy >= 0) & (hy < HO) & (hx >= 0) & (hx < WO);
            const float4* src = (const float4*)(hb + ((size_t)hy * WO + hx) * 16);
            #pragma unroll
            for (int v = 0; v < 4; ++v)
                htileV[v][i] = ok ? src[v] : make_float4(0.f, 0.f, 0.f, 0.f);
        }
    }
    __syncthreads();

    if (!active) return;

    int r = gy * WO + gx;
    size_t pt = (size_t)b * (TT*SPIX) + (size_t)t * SPIX + r;
    int ch0 = cg * 2;

    float z[8];
    #pragma unroll
    for (int c = 0; c < 2; ++c)
        #pragma unroll
        for (int g = 0; g < 4; ++g)
            z[c*4 + g] = __bfloat162float(zx[(size_t)(g*16 + ch0 + c) * NPT + pt]);

    f2 acc[4];
    #pragma unroll
    for (int i = 0; i < 4; ++i) { acc[i].x = 0.f; acc[i].y = 0.f; }

    #pragma unroll 1
    for (int tap = 0; tap < 9; ++tap) {
        int ky = tap / 3;
        int kx = tap - ky * 3;
        int pix = (ly + ky)*20 + (lx + kx);
        float h[16];
        #pragma unroll
        for (int v = 0; v < 4; ++v) {
            float4 t4 = htileV[v][pix];
            h[v*4+0] = t4.x; h[v*4+1] = t4.y; h[v*4+2] = t4.z; h[v*4+3] = t4.w;
        }
        const float* wt = wcg + tap * 128;
        #pragma unroll 1
        for (int hf = 0; hf < 2; ++hf) {
            const f2* wv = (const f2*)(wt + hf * 64);
            #pragma unroll
            for (int u = 0; u < 8; ++u) {
                float hv = h[hf*8 + u];
                acc[0] += hv * wv[u*4 + 0];
                acc[1] += hv * wv[u*4 + 1];
                acc[2] += hv * wv[u*4 + 2];
                acc[3] += hv * wv[u*4 + 3];
            }
        }
    }

    size_t base = ((size_t)(b * SPIX + r)) * 16 + ch0;
    float2 cold = *(float2*)&cst[base];
    float cn[2], hn[2];
    #pragma unroll
    for (int c = 0; c < 2; ++c) {
        float iv = hsig(z[c*4+0] + acc[c*2+0].x + bias[ 0 + ch0 + c]);
        float fv = hsig(z[c*4+1] + acc[c*2+0].y + bias[16 + ch0 + c]);
        float gv = tanhf(z[c*4+2] + acc[c*2+1].x + bias[32 + ch0 + c]);
        float ov = hsig(z[c*4+3] + acc[c*2+1].y + bias[48 + ch0 + c]);
        float cold_c = (c == 0) ? cold.x : cold.y;
        cn[c] = fv * cold_c + iv * gv;
        hn[c] = ov * tanhf(cn[c]);
    }
    *(float2*)&cst[base]   = make_float2(cn[0], cn[1]);
    *(float2*)&h_out[base] = make_float2(hn[0], hn[1]);
}

// Kernel 3: spatial mean over 54x54 -> dense(16->6) -> softmax. One block per b.
__global__ __launch_bounds__(256) void head_kernel(
    const float* __restrict__ h,    // [8,54,54,16]
    const float* __restrict__ dw,   // [16,6]
    const float* __restrict__ db,   // [6]
    float* __restrict__ out)        // [8,6]
{
    int b = blockIdx.x;
    int tid = threadIdx.x;
    const float* hb = h + (size_t)b * SPIX * 16;
    float s = 0.0f;
    for (int i = tid; i < SPIX*16; i += 256) s += hb[i];
    __shared__ float red[256];
    red[tid] = s;
    __syncthreads();
    for (int st = 128; st >= 16; st >>= 1) {
        if (tid < st) red[tid] += red[tid + st];
        __syncthreads();
    }
    __shared__ float logits[8];
    if (tid < NC) {
        float l = db[tid];
        #pragma unroll
        for (int ch = 0; ch < 16; ++ch)
            l += (red[ch] * (1.0f/2916.0f)) * dw[ch*NC + tid];
        logits[tid] = l;
    }
    __syncthreads();
    if (tid < NC) {
        float m = -1e30f;
        for (int k = 0; k < NC; ++k) m = fmaxf(m, logits[k]);
        float e = expf(logits[tid] - m);
        float d = 0.0f;
        for (int k = 0; k < NC; ++k) d += expf(logits[k] - m);
        out[b*NC + tid] = e / d;
    }
}

extern "C" void kernel_launch(void* const* d_in, const int* in_sizes, int n_in,
                              void* d_out, int out_size, void* d_ws, size_t ws_size,
                              hipStream_t stream) {
    const float* x      = (const float*)d_in[0];
    const float* conv_w = (const float*)d_in[1];
    const float* conv_b = (const float*)d_in[2];
    const float* wk     = (const float*)d_in[3];
    const float* wr     = (const float*)d_in[4];
    const float* bias   = (const float*)d_in[5];
    const float* dw     = (const float*)d_in[6];
    const float* db     = (const float*)d_in[7];
    float* out = (float*)d_out;

    float* ws     = (float*)d_ws;
    float* pooled = ws;                                   // 6,422,528 f
    float* hA     = pooled + POOLED_ELEMS;                //   373,248 f
    float* hB     = hA + HSTATE_ELEMS;
    float* cbuf   = hB + HSTATE_ELEMS;
    float* wpack  = cbuf + HSTATE_ELEMS;                  //     9,216 f (wrpack)
    __hip_bfloat16* zx = (__hip_bfloat16*)(wpack + WPACK_ELEMS); // 47.8 MB

    // h0 = 0, c0 = 0 (ws is poisoned before every launch)
    hipMemsetAsync(hA,   0, HSTATE_ELEMS * sizeof(float), stream);
    hipMemsetAsync(cbuf, 0, HSTATE_ELEMS * sizeof(float), stream);

    repack_kernel<<<dim3(36), dim3(256), 0, stream>>>(wr, wpack);
    conv_pool_kernel<<<dim3(14, 128), dim3(256), 0, stream>>>(x, conv_w, conv_b, pooled);
    zx_all_kernel<<<dim3(1458, 2), dim3(256), 0, stream>>>(pooled, wk, zx);

    for (int t = 0; t < TT; ++t) {
        const float* hin  = (t & 1) ? hB : hA;
        float*       hout = (t & 1) ? hA : hB;
        lstm_step_kernel<<<dim3(12, 8, 8), dim3(256), 0, stream>>>(
            zx, hin, hout, cbuf, wpack, bias, t);
    }
    // t=15 (odd) wrote hA
    head_kernel<<<dim3(8), dim3(256), 0, stream>>>(hA, dw, db, out);
}